// Round 6
// baseline (218.838 us; speedup 1.0000x reference)
//
#include <hip/hip_runtime.h>

// Problem constants
#define Bn  16
#define Ln  224
#define K1n 8192
#define Pn  16
#define NCHUNK 32   // k-chunks per batch (256 k each)

// ws layout (floats):
//   ws_sum : [Bn][NCHUNK][Pn]   per-block partial sums
//   ws_max : [Bn][NCHUNK][Pn]   per-block partial maxes
//   ws_mid : [Bn][Pn]           h3 at k = K1/2
// Every slot unconditionally written by exactly one block -> no zeroing,
// no atomics, safe under the harness's 0xAA ws poison.

__device__ __forceinline__ float readlane_f(float v, int lane) {
    return __uint_as_float(__builtin_amdgcn_readlane(__float_as_uint(v), lane));
}

// ---------------------------------------------------------------------------
// Kernel 1: per-(b,k) compute h3[p]; per-block reduce sum/max over its 256 k.
// Grid: 512 blocks (32 per b), 256 threads, one k per thread (8 waves/CU).
// w3c broadcast via v_readlane: one 256B vector load per wave covers 4 rows
// (64 floats); readlane with compile-time lane index moves each value to an
// SGPR on the VALU pipe -> zero LDS / zero broadcast-VMEM in the hot loop.
// ---------------------------------------------------------------------------
__global__ __launch_bounds__(256) void k_stats(
    const float* __restrict__ y,      // [B, L, K1] f32
    const float* __restrict__ w3c,    // [1, L, P]  f32
    const float* __restrict__ sigma,  // [1]        f32
    float* __restrict__ ws_sum,
    float* __restrict__ ws_max,
    float* __restrict__ ws_mid)
{
    __shared__ float s_csq_part[16][Pn];
    __shared__ float s_csq[Pn];
    __shared__ float s_part_s[4][Pn];
    __shared__ float s_part_m[4][Pn];

    const int tid   = threadIdx.x;
    const int lane  = tid & 63;
    const int b     = blockIdx.x >> 5;         // 32 blocks per batch
    const int chunk = blockIdx.x & 31;
    const int k     = (chunk << 8) + tid;

    // c_sq[p] = sum_l w3c[l][p]^2 — cooperative prologue (outside hot loop)
    {
        const int p   = tid & 15;
        const int sub = tid >> 4;              // 0..15
        float cs = 0.f;
#pragma unroll
        for (int l = sub; l < Ln; l += 16) {
            float v = w3c[l * Pn + p];
            cs = fmaf(v, v, cs);
        }
        s_csq_part[sub][p] = cs;
    }
    __syncthreads();
    if (tid < Pn) {
        float cs = 0.f;
#pragma unroll
        for (int s = 0; s < 16; ++s) cs += s_csq_part[s][tid];
        s_csq[tid] = cs;
    }
    __syncthreads();

    // Main loop over L in quads of 4 rows. Each wave loads the 4-row chunk of
    // w3c (64 floats) with ONE coalesced dword load, then readlane-broadcasts.
    float cross[Pn];
#pragma unroll
    for (int p = 0; p < Pn; ++p) cross[p] = 0.f;
    float ysq = 0.f;

    const float* yp = y + (size_t)b * Ln * K1n + k;

    float wv = w3c[lane];                      // quad 0
#pragma unroll 2
    for (int q = 0; q < Ln / 4; ++q) {
        // prefetch next w3c quad
        float wv_next = (q < Ln / 4 - 1) ? w3c[(q + 1) * 64 + lane] : 0.f;
        // 4 y rows for this quad
        float v0 = yp[(size_t)(4 * q + 0) * K1n];
        float v1 = yp[(size_t)(4 * q + 1) * K1n];
        float v2 = yp[(size_t)(4 * q + 2) * K1n];
        float v3 = yp[(size_t)(4 * q + 3) * K1n];

        ysq = fmaf(v0, v0, ysq);
        ysq = fmaf(v1, v1, ysq);
        ysq = fmaf(v2, v2, ysq);
        ysq = fmaf(v3, v3, ysq);

#pragma unroll
        for (int p = 0; p < Pn; ++p) {
            cross[p] = fmaf(v0, readlane_f(wv,  0 * 16 + p), cross[p]);
            cross[p] = fmaf(v1, readlane_f(wv,  1 * 16 + p), cross[p]);
            cross[p] = fmaf(v2, readlane_f(wv,  2 * 16 + p), cross[p]);
            cross[p] = fmaf(v3, readlane_f(wv,  3 * 16 + p), cross[p]);
        }
        wv = wv_next;
    }

    const float sg = sigma[0];
    const float nh = -0.5f / (sg * sg);

    float h3[Pn];
#pragma unroll
    for (int p = 0; p < Pn; ++p) {
        float d = fmaxf(ysq + s_csq[p] - 2.f * cross[p], 0.f);
        h3[p] = __expf(d * nh);
    }

    // mid = h3[b, p, K1/2] : k == 4096 -> chunk == 16, tid == 0
    if (k == (K1n / 2)) {
#pragma unroll
        for (int p = 0; p < Pn; ++p) ws_mid[b * Pn + p] = h3[p];
    }

    // Wave-level reduce (sum & max) per p, then cross-wave via LDS
    const int wv_id = tid >> 6;
#pragma unroll
    for (int p = 0; p < Pn; ++p) {
        float s = h3[p];
        float m = h3[p];
#pragma unroll
        for (int off = 32; off > 0; off >>= 1) {
            s += __shfl_down(s, off, 64);
            m = fmaxf(m, __shfl_down(m, off, 64));
        }
        if (lane == 0) { s_part_s[wv_id][p] = s; s_part_m[wv_id][p] = m; }
    }
    __syncthreads();
    if (tid < Pn) {
        float s = s_part_s[0][tid] + s_part_s[1][tid] + s_part_s[2][tid] + s_part_s[3][tid];
        float m = fmaxf(fmaxf(s_part_m[0][tid], s_part_m[1][tid]),
                        fmaxf(s_part_m[2][tid], s_part_m[3][tid]));
        const int base = (b * NCHUNK + chunk) * Pn + tid;
        ws_sum[base] = s;
        ws_max[base] = m;
    }
}

// ---------------------------------------------------------------------------
// Kernel 2: reduce partials + tiny finalize (h4[b,p]) + out = h4 + w3_w@(a-d2).
// Grid: 512 blocks (32 per b), 256 threads, one k per thread. (unchanged —
// not the bottleneck)
// ---------------------------------------------------------------------------
__global__ __launch_bounds__(256) void k_out(
    const float* __restrict__ a,      // [B, P, K1] f32
    const float* __restrict__ d2,     // [B, P, K1] f32
    const float* __restrict__ w3w,    // [P, P] f32
    const float* __restrict__ b3w,    // [P, P] f32
    const float* __restrict__ caw,    // [2, P] f32
    const float* __restrict__ ws_sum,
    const float* __restrict__ ws_max,
    const float* __restrict__ ws_mid,
    float* __restrict__ out)          // [B, P, K1] f32
{
    __shared__ float s_w3w[Pn][Pn];
    __shared__ float s_red_s[16][Pn];   // 16 groups x 16 p
    __shared__ float s_red_m[16][Pn];
    __shared__ float s_avg[Pn], s_mx[Pn], s_mid[Pn], s_comb[Pn], s_h4[Pn];
    __shared__ float s_t[2];

    const int tid = threadIdx.x;
    const int b   = blockIdx.x >> 5;
    const int k   = ((blockIdx.x & 31) << 8) + tid;

    if (tid < Pn * Pn) s_w3w[tid >> 4][tid & 15] = w3w[tid];

    // Parallel partial-reduce: thread (grp, p) handles chunks grp and grp+16
    {
        const int p   = tid & 15;
        const int grp = tid >> 4;          // 0..15
        const int i0  = (b * NCHUNK + grp)      * Pn + p;
        const int i1  = (b * NCHUNK + grp + 16) * Pn + p;
        s_red_s[grp][p] = ws_sum[i0] + ws_sum[i1];
        s_red_m[grp][p] = fmaxf(ws_max[i0], ws_max[i1]);
    }
    __syncthreads();
    if (tid < Pn) {
        float s = 0.f, m = -1.f;
        for (int g = 0; g < 16; ++g) {
            s += s_red_s[g][tid];
            m = fmaxf(m, s_red_m[g][tid]);
        }
        s_avg[tid] = s * (1.f / (float)K1n);
        s_mx[tid]  = m;
        s_mid[tid] = ws_mid[b * Pn + tid];
    }
    __syncthreads();

    if (tid < 2) {
        float t1 = 0.f, t2 = 0.f;
        for (int p = 0; p < Pn; ++p) {
            float cw = caw[tid * Pn + p];
            t1 = fmaf(cw, s_avg[p], t1);
            t2 = fmaf(cw, s_mx[p],  t2);
        }
        t1 = (t1 > 0.f) ? t1 : 0.01f * t1;   // leaky_relu
        t2 = (t2 > 0.f) ? t2 : 0.01f * t2;
        s_t[tid] = t1 + t2;
    }
    __syncthreads();

    if (tid < Pn) {
        float t0 = s_t[0], u1 = s_t[1];
        float mt = fmaxf(t0, u1);
        float e0 = __expf(t0 - mt), e1 = __expf(u1 - mt);
        float inv = 1.f / (e0 + e1);
        s_comb[tid] = (e0 * inv) * s_mid[tid] + (e1 * inv) * s_avg[tid];
    }
    __syncthreads();

    if (tid < Pn) {
        float h = 0.f;
        for (int q = 0; q < Pn; ++q) h = fmaf(b3w[tid * Pn + q], s_comb[q], h);
        s_h4[tid] = h;
    }
    __syncthreads();

    // Main: diff[q] = (a - d2)[b, q, k]; out[b, p, k] = h4[p] + w3_w[p,:]·diff
    const size_t base = (size_t)b * Pn * K1n + (size_t)k;
    float diff[Pn];
#pragma unroll
    for (int q = 0; q < Pn; ++q) {
        float av = a [base + (size_t)q * K1n];
        float dv = d2[base + (size_t)q * K1n];
        diff[q] = av - dv;
    }
#pragma unroll
    for (int p = 0; p < Pn; ++p) {
        float h2 = 0.f;
#pragma unroll
        for (int q = 0; q < Pn; ++q) h2 = fmaf(s_w3w[p][q], diff[q], h2);
        out[base + (size_t)p * K1n] = h2 + s_h4[p];
    }
}

// ---------------------------------------------------------------------------
extern "C" void kernel_launch(void* const* d_in, const int* in_sizes, int n_in,
                              void* d_out, int out_size, void* d_ws, size_t ws_size,
                              hipStream_t stream) {
    const float* a     = (const float*)d_in[0];
    const float* d2    = (const float*)d_in[1];
    const float* y     = (const float*)d_in[2];
    const float* w3w   = (const float*)d_in[3];
    const float* b3w   = (const float*)d_in[4];
    const float* w3c   = (const float*)d_in[5];
    const float* sigma = (const float*)d_in[6];
    const float* caw   = (const float*)d_in[7];

    float* ws_sum = (float*)d_ws;
    float* ws_max = ws_sum + Bn * NCHUNK * Pn;
    float* ws_mid = ws_max + Bn * NCHUNK * Pn;

    k_stats<<<dim3(Bn * NCHUNK), dim3(256), 0, stream>>>(
        y, w3c, sigma, ws_sum, ws_max, ws_mid);

    k_out<<<dim3(Bn * NCHUNK), dim3(256), 0, stream>>>(
        a, d2, w3w, b3w, caw, ws_sum, ws_max, ws_mid, (float*)d_out);
}

// Round 7
// 214.134 us; speedup vs baseline: 1.0220x; 1.0220x over previous
//
#include <hip/hip_runtime.h>

// Problem constants
#define Bn  16
#define Ln  224
#define K1n 8192
#define Pn  16
#define NCHUNK 32   // k-chunks per batch (256 k each)
#define CH  28      // l-rows per staged chunk (224 = 8 * 28)

// ws layout (floats):
//   ws_sum : [Bn][NCHUNK][Pn]   per-block partial sums
//   ws_max : [Bn][NCHUNK][Pn]   per-block partial maxes
//   ws_mid : [Bn][Pn]           h3 at k = K1/2
// Every slot unconditionally written by exactly one block -> no zeroing,
// no atomics, safe under the harness's 0xAA ws poison.

__device__ __forceinline__ float readlane_f(float v, int lane) {
    return __uint_as_float(__builtin_amdgcn_readlane(__float_as_uint(v), lane));
}

// async global->LDS DMA, 4 B per lane (wave writes 256 B at lds base + lane*4)
__device__ __forceinline__ void async_copy_dword(const float* g, float* l) {
    __builtin_amdgcn_global_load_lds(
        (const __attribute__((address_space(1))) unsigned int*)g,
        (__attribute__((address_space(3))) unsigned int*)l, 4, 0, 0);
}

// ---------------------------------------------------------------------------
// Kernel 1: per-(b,k) compute h3[p]; per-block reduce sum/max over its 256 k.
// Grid: 512 blocks (32 per b), 256 threads, one k per thread (8 waves/CU).
// y is staged global->LDS via async DMA (double-buffered 28-row chunks) so
// load latency is decoupled from the FMA chain; w3c broadcast via readlane
// from per-wave registers (VALU pipe; LDS pipe stays ~free: 1 ds_read_b32
// per l per wave, 2-way bank aliasing).
// ---------------------------------------------------------------------------
__global__ __launch_bounds__(256) void k_stats(
    const float* __restrict__ y,      // [B, L, K1] f32
    const float* __restrict__ w3c,    // [1, L, P]  f32
    const float* __restrict__ sigma,  // [1]        f32
    float* __restrict__ ws_sum,
    float* __restrict__ ws_max,
    float* __restrict__ ws_mid)
{
    __shared__ float s_y[2][CH][256];     // 56 KiB double buffer
    __shared__ float s_csq_part[16][Pn];
    __shared__ float s_csq[Pn];
    __shared__ float s_part_s[4][Pn];
    __shared__ float s_part_m[4][Pn];

    const int tid   = threadIdx.x;
    const int lane  = tid & 63;
    const int wv    = tid >> 6;
    const int b     = blockIdx.x >> 5;         // 32 blocks per batch
    const int chunk = blockIdx.x & 31;
    const int k     = (chunk << 8) + tid;

    // c_sq[p] = sum_l w3c[l][p]^2 — cooperative prologue
    {
        const int p   = tid & 15;
        const int sub = tid >> 4;              // 0..15
        float cs = 0.f;
#pragma unroll
        for (int l = sub; l < Ln; l += 16) {
            float v = w3c[l * Pn + p];
            cs = fmaf(v, v, cs);
        }
        s_csq_part[sub][p] = cs;
    }
    __syncthreads();
    if (tid < Pn) {
        float cs = 0.f;
#pragma unroll
        for (int s = 0; s < 16; ++s) cs += s_csq_part[s][tid];
        s_csq[tid] = cs;
    }

    float cross[Pn];
#pragma unroll
    for (int p = 0; p < Pn; ++p) cross[p] = 0.f;
    float ysq = 0.f;

    // per-lane global source for this wave's 64-k column slice
    const float* ybase = y + (size_t)b * Ln * K1n + (chunk << 8) + (wv << 6) + lane;

    // w3c quad registers: wq[q] holds rows 4q..4q+3 of the current chunk
    // (64 floats across the wave); readlane broadcasts at compile-time index.
    float wq[7], wqn[7];
#pragma unroll
    for (int q = 0; q < 7; ++q) wq[q] = w3c[q * 64 + lane];

    // prologue: DMA chunk 0
    for (int l = 0; l < CH; ++l)
        async_copy_dword(ybase + (size_t)l * K1n, &s_y[0][l][wv << 6]);
    __syncthreads();   // drains vmcnt -> chunk 0 resident

    for (int c = 0; c < Ln / CH; ++c) {
        const int cb = c & 1;
        if (c < Ln / CH - 1) {
            const int nb = cb ^ 1;
#pragma unroll
            for (int q = 0; q < 7; ++q)
                wqn[q] = w3c[((c + 1) * CH) * Pn + q * 64 + lane];
            for (int l = 0; l < CH; ++l)
                async_copy_dword(ybase + (size_t)((c + 1) * CH + l) * K1n,
                                 &s_y[nb][l][wv << 6]);
        }
        // consume current chunk from LDS
#pragma unroll
        for (int q = 0; q < 7; ++q) {
            float v0 = s_y[cb][q * 4 + 0][tid];
            float v1 = s_y[cb][q * 4 + 1][tid];
            float v2 = s_y[cb][q * 4 + 2][tid];
            float v3 = s_y[cb][q * 4 + 3][tid];
            ysq = fmaf(v0, v0, ysq);
            ysq = fmaf(v1, v1, ysq);
            ysq = fmaf(v2, v2, ysq);
            ysq = fmaf(v3, v3, ysq);
#pragma unroll
            for (int p = 0; p < Pn; ++p) {
                cross[p] = fmaf(v0, readlane_f(wq[q],  0 + p), cross[p]);
                cross[p] = fmaf(v1, readlane_f(wq[q], 16 + p), cross[p]);
                cross[p] = fmaf(v2, readlane_f(wq[q], 32 + p), cross[p]);
                cross[p] = fmaf(v3, readlane_f(wq[q], 48 + p), cross[p]);
            }
        }
#pragma unroll
        for (int q = 0; q < 7; ++q) wq[q] = wqn[q];
        __syncthreads();   // next-chunk DMA drained; buffer swap safe
    }

    const float sg = sigma[0];
    const float nh = -0.5f / (sg * sg);

    float h3[Pn];
#pragma unroll
    for (int p = 0; p < Pn; ++p) {
        float d = fmaxf(ysq + s_csq[p] - 2.f * cross[p], 0.f);
        h3[p] = __expf(d * nh);
    }

    // mid = h3[b, p, K1/2] : k == 4096 -> chunk == 16, tid == 0
    if (k == (K1n / 2)) {
#pragma unroll
        for (int p = 0; p < Pn; ++p) ws_mid[b * Pn + p] = h3[p];
    }

    // Wave-level reduce (sum & max) per p, then cross-wave via LDS
#pragma unroll
    for (int p = 0; p < Pn; ++p) {
        float s = h3[p];
        float m = h3[p];
#pragma unroll
        for (int off = 32; off > 0; off >>= 1) {
            s += __shfl_down(s, off, 64);
            m = fmaxf(m, __shfl_down(m, off, 64));
        }
        if (lane == 0) { s_part_s[wv][p] = s; s_part_m[wv][p] = m; }
    }
    __syncthreads();
    if (tid < Pn) {
        float s = s_part_s[0][tid] + s_part_s[1][tid] + s_part_s[2][tid] + s_part_s[3][tid];
        float m = fmaxf(fmaxf(s_part_m[0][tid], s_part_m[1][tid]),
                        fmaxf(s_part_m[2][tid], s_part_m[3][tid]));
        const int base = (b * NCHUNK + chunk) * Pn + tid;
        ws_sum[base] = s;
        ws_max[base] = m;
    }
}

// ---------------------------------------------------------------------------
// Kernel 2: reduce partials + tiny finalize (h4[b,p]) + out = h4 + w3_w@(a-d2).
// Grid: 512 blocks (32 per b), 256 threads, one k per thread. (unchanged —
// not the bottleneck)
// ---------------------------------------------------------------------------
__global__ __launch_bounds__(256) void k_out(
    const float* __restrict__ a,      // [B, P, K1] f32
    const float* __restrict__ d2,     // [B, P, K1] f32
    const float* __restrict__ w3w,    // [P, P] f32
    const float* __restrict__ b3w,    // [P, P] f32
    const float* __restrict__ caw,    // [2, P] f32
    const float* __restrict__ ws_sum,
    const float* __restrict__ ws_max,
    const float* __restrict__ ws_mid,
    float* __restrict__ out)          // [B, P, K1] f32
{
    __shared__ float s_w3w[Pn][Pn];
    __shared__ float s_red_s[16][Pn];   // 16 groups x 16 p
    __shared__ float s_red_m[16][Pn];
    __shared__ float s_avg[Pn], s_mx[Pn], s_mid[Pn], s_comb[Pn], s_h4[Pn];
    __shared__ float s_t[2];

    const int tid = threadIdx.x;
    const int b   = blockIdx.x >> 5;
    const int k   = ((blockIdx.x & 31) << 8) + tid;

    if (tid < Pn * Pn) s_w3w[tid >> 4][tid & 15] = w3w[tid];

    // Parallel partial-reduce: thread (grp, p) handles chunks grp and grp+16
    {
        const int p   = tid & 15;
        const int grp = tid >> 4;          // 0..15
        const int i0  = (b * NCHUNK + grp)      * Pn + p;
        const int i1  = (b * NCHUNK + grp + 16) * Pn + p;
        s_red_s[grp][p] = ws_sum[i0] + ws_sum[i1];
        s_red_m[grp][p] = fmaxf(ws_max[i0], ws_max[i1]);
    }
    __syncthreads();
    if (tid < Pn) {
        float s = 0.f, m = -1.f;
        for (int g = 0; g < 16; ++g) {
            s += s_red_s[g][tid];
            m = fmaxf(m, s_red_m[g][tid]);
        }
        s_avg[tid] = s * (1.f / (float)K1n);
        s_mx[tid]  = m;
        s_mid[tid] = ws_mid[b * Pn + tid];
    }
    __syncthreads();

    if (tid < 2) {
        float t1 = 0.f, t2 = 0.f;
        for (int p = 0; p < Pn; ++p) {
            float cw = caw[tid * Pn + p];
            t1 = fmaf(cw, s_avg[p], t1);
            t2 = fmaf(cw, s_mx[p],  t2);
        }
        t1 = (t1 > 0.f) ? t1 : 0.01f * t1;   // leaky_relu
        t2 = (t2 > 0.f) ? t2 : 0.01f * t2;
        s_t[tid] = t1 + t2;
    }
    __syncthreads();

    if (tid < Pn) {
        float t0 = s_t[0], u1 = s_t[1];
        float mt = fmaxf(t0, u1);
        float e0 = __expf(t0 - mt), e1 = __expf(u1 - mt);
        float inv = 1.f / (e0 + e1);
        s_comb[tid] = (e0 * inv) * s_mid[tid] + (e1 * inv) * s_avg[tid];
    }
    __syncthreads();

    if (tid < Pn) {
        float h = 0.f;
        for (int q = 0; q < Pn; ++q) h = fmaf(b3w[tid * Pn + q], s_comb[q], h);
        s_h4[tid] = h;
    }
    __syncthreads();

    // Main: diff[q] = (a - d2)[b, q, k]; out[b, p, k] = h4[p] + w3_w[p,:]·diff
    const size_t base = (size_t)b * Pn * K1n + (size_t)k;
    float diff[Pn];
#pragma unroll
    for (int q = 0; q < Pn; ++q) {
        float av = a [base + (size_t)q * K1n];
        float dv = d2[base + (size_t)q * K1n];
        diff[q] = av - dv;
    }
#pragma unroll
    for (int p = 0; p < Pn; ++p) {
        float h2 = 0.f;
#pragma unroll
        for (int q = 0; q < Pn; ++q) h2 = fmaf(s_w3w[p][q], diff[q], h2);
        out[base + (size_t)p * K1n] = h2 + s_h4[p];
    }
}

// ---------------------------------------------------------------------------
extern "C" void kernel_launch(void* const* d_in, const int* in_sizes, int n_in,
                              void* d_out, int out_size, void* d_ws, size_t ws_size,
                              hipStream_t stream) {
    const float* a     = (const float*)d_in[0];
    const float* d2    = (const float*)d_in[1];
    const float* y     = (const float*)d_in[2];
    const float* w3w   = (const float*)d_in[3];
    const float* b3w   = (const float*)d_in[4];
    const float* w3c   = (const float*)d_in[5];
    const float* sigma = (const float*)d_in[6];
    const float* caw   = (const float*)d_in[7];

    float* ws_sum = (float*)d_ws;
    float* ws_max = ws_sum + Bn * NCHUNK * Pn;
    float* ws_mid = ws_max + Bn * NCHUNK * Pn;

    k_stats<<<dim3(Bn * NCHUNK), dim3(256), 0, stream>>>(
        y, w3c, sigma, ws_sum, ws_max, ws_mid);

    k_out<<<dim3(Bn * NCHUNK), dim3(256), 0, stream>>>(
        a, d2, w3w, b3w, caw, ws_sum, ws_max, ws_mid, (float*)d_out);
}

// Round 8
// 208.864 us; speedup vs baseline: 1.0478x; 1.0252x over previous
//
#include <hip/hip_runtime.h>

// Problem constants
#define Bn  16
#define Ln  224
#define K1n 8192
#define Pn  16
#define NCHUNK 16   // k-chunks per batch (512 k each, float2 per thread)

// ws layout (floats):
//   ws_sum : [Bn][NCHUNK][Pn]   per-block partial sums
//   ws_max : [Bn][NCHUNK][Pn]   per-block partial maxes
//   ws_mid : [Bn][Pn]           h3 at k = K1/2
// Every slot unconditionally written by exactly one block -> no zeroing,
// no atomics, safe under the harness's 0xAA ws poison.

__device__ __forceinline__ float readlane_f(float v, int lane) {
    return __uint_as_float(__builtin_amdgcn_readlane(__float_as_uint(v), lane));
}

// ---------------------------------------------------------------------------
// Kernel 1: per-(b,k) compute h3[p]; per-block reduce sum/max over its 512 k.
// Grid: 256 blocks (16 per b), 256 threads, TWO k per thread (float2).
// Each block consumes a contiguous 2 KiB span of every y row (full DRAM page
// per visit — the page-locality fix). w3c via readlane broadcast (VALU pipe,
// no LDS / no syncthreads in the hot loop). Manual 8-row prefetch pipeline
// keeps ~4 KiB per wave in flight.
// ---------------------------------------------------------------------------
__global__ __launch_bounds__(256, 1) void k_stats(
    const float* __restrict__ y,      // [B, L, K1] f32
    const float* __restrict__ w3c,    // [1, L, P]  f32
    const float* __restrict__ sigma,  // [1]        f32
    float* __restrict__ ws_sum,
    float* __restrict__ ws_max,
    float* __restrict__ ws_mid)
{
    __shared__ float s_csq_part[16][Pn];
    __shared__ float s_csq[Pn];
    __shared__ float s_part_s[4][Pn];
    __shared__ float s_part_m[4][Pn];

    const int tid   = threadIdx.x;
    const int lane  = tid & 63;
    const int wv    = tid >> 6;
    const int b     = blockIdx.x >> 4;         // 16 blocks per batch
    const int chunk = blockIdx.x & 15;

    // c_sq[p] = sum_l w3c[l][p]^2 — cooperative prologue
    {
        const int p   = tid & 15;
        const int sub = tid >> 4;              // 0..15
        float cs = 0.f;
#pragma unroll
        for (int l = sub; l < Ln; l += 16) {
            float v = w3c[l * Pn + p];
            cs = fmaf(v, v, cs);
        }
        s_csq_part[sub][p] = cs;
    }
    __syncthreads();
    if (tid < Pn) {
        float cs = 0.f;
#pragma unroll
        for (int s = 0; s < 16; ++s) cs += s_csq_part[s][tid];
        s_csq[tid] = cs;
    }
    __syncthreads();

    float cross0[Pn], cross1[Pn];
#pragma unroll
    for (int p = 0; p < Pn; ++p) { cross0[p] = 0.f; cross1[p] = 0.f; }
    float ysq0 = 0.f, ysq1 = 0.f;

    // per-thread float2 source: contiguous 2 KiB per row across the block
    const float2* yp2 = reinterpret_cast<const float2*>(
                            y + (size_t)b * Ln * K1n + (chunk << 9)) + tid;

    // 8-row software pipeline; w3c rows 8g..8g+7 live in wqa (rows 8g..8g+3,
    // 64 floats across the wave) and wqb (rows 8g+4..8g+7).
    float2 v[8], vn[8];
    float wqa = w3c[lane], wqb = w3c[64 + lane], wqan, wqbn;
#pragma unroll
    for (int j = 0; j < 8; ++j) v[j] = yp2[(size_t)j * (K1n / 2)];

    for (int g = 0; g < Ln / 8; ++g) {
        if (g < Ln / 8 - 1) {
            wqan = w3c[(g + 1) * 128 + lane];
            wqbn = w3c[(g + 1) * 128 + 64 + lane];
#pragma unroll
            for (int j = 0; j < 8; ++j)
                vn[j] = yp2[(size_t)((g + 1) * 8 + j) * (K1n / 2)];
        }
#pragma unroll
        for (int j = 0; j < 8; ++j) {
            const float wreg = (j < 4) ? wqa : wqb;
            ysq0 = fmaf(v[j].x, v[j].x, ysq0);
            ysq1 = fmaf(v[j].y, v[j].y, ysq1);
#pragma unroll
            for (int p = 0; p < Pn; ++p) {
                float w = readlane_f(wreg, (j & 3) * 16 + p);
                cross0[p] = fmaf(v[j].x, w, cross0[p]);
                cross1[p] = fmaf(v[j].y, w, cross1[p]);
            }
        }
        wqa = wqan; wqb = wqbn;
#pragma unroll
        for (int j = 0; j < 8; ++j) v[j] = vn[j];
    }

    const float sg = sigma[0];
    const float nh = -0.5f / (sg * sg);

    float h3e[Pn], h3o[Pn];
#pragma unroll
    for (int p = 0; p < Pn; ++p) {
        float de = fmaxf(ysq0 + s_csq[p] - 2.f * cross0[p], 0.f);
        float dd = fmaxf(ysq1 + s_csq[p] - 2.f * cross1[p], 0.f);
        h3e[p] = __expf(de * nh);
        h3o[p] = __expf(dd * nh);
    }

    // mid = h3[b, p, K1/2] : k == 4096 -> chunk == 8, tid == 0, even element
    if (chunk == 8 && tid == 0) {
#pragma unroll
        for (int p = 0; p < Pn; ++p) ws_mid[b * Pn + p] = h3e[p];
    }

    // Wave-level reduce (sum & max) per p, then cross-wave via LDS
#pragma unroll
    for (int p = 0; p < Pn; ++p) {
        float s = h3e[p] + h3o[p];
        float m = fmaxf(h3e[p], h3o[p]);
#pragma unroll
        for (int off = 32; off > 0; off >>= 1) {
            s += __shfl_down(s, off, 64);
            m = fmaxf(m, __shfl_down(m, off, 64));
        }
        if (lane == 0) { s_part_s[wv][p] = s; s_part_m[wv][p] = m; }
    }
    __syncthreads();
    if (tid < Pn) {
        float s = s_part_s[0][tid] + s_part_s[1][tid] + s_part_s[2][tid] + s_part_s[3][tid];
        float m = fmaxf(fmaxf(s_part_m[0][tid], s_part_m[1][tid]),
                        fmaxf(s_part_m[2][tid], s_part_m[3][tid]));
        const int base = (b * NCHUNK + chunk) * Pn + tid;
        ws_sum[base] = s;
        ws_max[base] = m;
    }
}

// ---------------------------------------------------------------------------
// Kernel 2: reduce partials + tiny finalize (h4[b,p]) + out = h4 + w3_w@(a-d2).
// Grid: 256 blocks (16 per b), 256 threads, two k per thread (float2) —
// 2 KiB contiguous per row visit, same page-locality fix.
// ---------------------------------------------------------------------------
__global__ __launch_bounds__(256, 1) void k_out(
    const float* __restrict__ a,      // [B, P, K1] f32
    const float* __restrict__ d2,     // [B, P, K1] f32
    const float* __restrict__ w3w,    // [P, P] f32
    const float* __restrict__ b3w,    // [P, P] f32
    const float* __restrict__ caw,    // [2, P] f32
    const float* __restrict__ ws_sum,
    const float* __restrict__ ws_max,
    const float* __restrict__ ws_mid,
    float* __restrict__ out)          // [B, P, K1] f32
{
    __shared__ float s_w3w[Pn][Pn];
    __shared__ float s_red_s[16][Pn];   // 16 chunks x 16 p
    __shared__ float s_red_m[16][Pn];
    __shared__ float s_avg[Pn], s_mx[Pn], s_mid[Pn], s_comb[Pn], s_h4[Pn];
    __shared__ float s_t[2];

    const int tid = threadIdx.x;
    const int b   = blockIdx.x >> 4;
    const int kb  = (blockIdx.x & 15) << 9;   // 512 k per block

    if (tid < Pn * Pn) s_w3w[tid >> 4][tid & 15] = w3w[tid];

    // Parallel partial-reduce: thread (grp, p) reads chunk grp
    {
        const int p   = tid & 15;
        const int grp = tid >> 4;          // 0..15
        const int i0  = (b * NCHUNK + grp) * Pn + p;
        s_red_s[grp][p] = ws_sum[i0];
        s_red_m[grp][p] = ws_max[i0];
    }
    __syncthreads();
    if (tid < Pn) {
        float s = 0.f, m = -1.f;
#pragma unroll
        for (int g = 0; g < 16; ++g) {
            s += s_red_s[g][tid];
            m = fmaxf(m, s_red_m[g][tid]);
        }
        s_avg[tid] = s * (1.f / (float)K1n);
        s_mx[tid]  = m;
        s_mid[tid] = ws_mid[b * Pn + tid];
    }
    __syncthreads();

    if (tid < 2) {
        float t1 = 0.f, t2 = 0.f;
        for (int p = 0; p < Pn; ++p) {
            float cw = caw[tid * Pn + p];
            t1 = fmaf(cw, s_avg[p], t1);
            t2 = fmaf(cw, s_mx[p],  t2);
        }
        t1 = (t1 > 0.f) ? t1 : 0.01f * t1;   // leaky_relu
        t2 = (t2 > 0.f) ? t2 : 0.01f * t2;
        s_t[tid] = t1 + t2;
    }
    __syncthreads();

    if (tid < Pn) {
        float t0 = s_t[0], u1 = s_t[1];
        float mt = fmaxf(t0, u1);
        float e0 = __expf(t0 - mt), e1 = __expf(u1 - mt);
        float inv = 1.f / (e0 + e1);
        s_comb[tid] = (e0 * inv) * s_mid[tid] + (e1 * inv) * s_avg[tid];
    }
    __syncthreads();

    if (tid < Pn) {
        float h = 0.f;
        for (int q = 0; q < Pn; ++q) h = fmaf(b3w[tid * Pn + q], s_comb[q], h);
        s_h4[tid] = h;
    }
    __syncthreads();

    // diff[q] = (a - d2)[b, q, k..k+1]; out[b,p,k..k+1] = h4[p] + w3_w[p,:]·diff
    const float2* a2 = reinterpret_cast<const float2*>(
                           a  + (size_t)b * Pn * K1n + kb) + tid;
    const float2* d22 = reinterpret_cast<const float2*>(
                           d2 + (size_t)b * Pn * K1n + kb) + tid;
    float2* o2 = reinterpret_cast<float2*>(
                           out + (size_t)b * Pn * K1n + kb) + tid;

    float2 av[Pn], dv[Pn];
#pragma unroll
    for (int q = 0; q < Pn; ++q) av[q] = a2 [(size_t)q * (K1n / 2)];
#pragma unroll
    for (int q = 0; q < Pn; ++q) dv[q] = d22[(size_t)q * (K1n / 2)];

    float2 diff[Pn];
#pragma unroll
    for (int q = 0; q < Pn; ++q) {
        diff[q].x = av[q].x - dv[q].x;
        diff[q].y = av[q].y - dv[q].y;
    }
#pragma unroll
    for (int p = 0; p < Pn; ++p) {
        float2 h2;
        h2.x = h2.y = s_h4[p];
#pragma unroll
        for (int q = 0; q < Pn; ++q) {
            const float w = s_w3w[p][q];
            h2.x = fmaf(w, diff[q].x, h2.x);
            h2.y = fmaf(w, diff[q].y, h2.y);
        }
        o2[(size_t)p * (K1n / 2)] = h2;
    }
}

// ---------------------------------------------------------------------------
extern "C" void kernel_launch(void* const* d_in, const int* in_sizes, int n_in,
                              void* d_out, int out_size, void* d_ws, size_t ws_size,
                              hipStream_t stream) {
    const float* a     = (const float*)d_in[0];
    const float* d2    = (const float*)d_in[1];
    const float* y     = (const float*)d_in[2];
    const float* w3w   = (const float*)d_in[3];
    const float* b3w   = (const float*)d_in[4];
    const float* w3c   = (const float*)d_in[5];
    const float* sigma = (const float*)d_in[6];
    const float* caw   = (const float*)d_in[7];

    float* ws_sum = (float*)d_ws;
    float* ws_max = ws_sum + Bn * NCHUNK * Pn;
    float* ws_mid = ws_max + Bn * NCHUNK * Pn;

    k_stats<<<dim3(Bn * NCHUNK), dim3(256), 0, stream>>>(
        y, w3c, sigma, ws_sum, ws_max, ws_mid);

    k_out<<<dim3(Bn * NCHUNK), dim3(256), 0, stream>>>(
        a, d2, w3w, b3w, caw, ws_sum, ws_max, ws_mid, (float*)d_out);
}